// Round 16
// baseline (146.907 us; speedup 1.0000x reference)
//
#include <hip/hip_runtime.h>
#include <hip/hip_bf16.h>
#include <stdint.h>

#define DIM 256

typedef float f32x4  __attribute__((ext_vector_type(4)));
typedef float f32x16 __attribute__((ext_vector_type(16)));
typedef short bf16x8 __attribute__((ext_vector_type(8)));
typedef short bf16x4 __attribute__((ext_vector_type(4)));
typedef unsigned int u32x2 __attribute__((ext_vector_type(2)));

__device__ __forceinline__ unsigned short f2bf(float f) {
  union { float f; uint32_t u; } v; v.f = f;
  uint32_t u = v.u;
  u += 0x7FFFu + ((u >> 16) & 1u);   // round-to-nearest-even
  return (unsigned short)(u >> 16);
}

// packed f32x2 -> bf16x2 (RNE), single instruction
__device__ __forceinline__ uint32_t pack2(float lo, float hi) {
  uint32_t r;
  asm("v_cvt_pk_bf16_f32 %0, %1, %2" : "=v"(r) : "v"(lo), "v"(hi));
  return r;
}

// async global->LDS, 16B per lane; LDS dest = wave-uniform base (+ lane*16 by HW)
__device__ __forceinline__ void gload16(const unsigned short* g, unsigned short* l) {
  __builtin_amdgcn_global_load_lds(
      (const __attribute__((address_space(1))) unsigned int*)g,
      (__attribute__((address_space(3))) unsigned int*)l, 16, 0, 0);
}

// ---- prep: W -> MFMA-fragment layout WF[(w*16+nt)*8+kc][512] via LDS tile
//      (blocks 0..23); x column partial sums, 32 rows/block (blocks 24..) ----
__global__ __launch_bounds__(256) void k_prep(const float* __restrict__ Wq,
    const float* __restrict__ Wk, const float* __restrict__ Wv,
    unsigned short* __restrict__ Wt, const float* __restrict__ x,
    float* __restrict__ partial, int n) {
  __shared__ unsigned short WL32[32][264];
  if (blockIdx.x < 24) {
    const int w  = blockIdx.x >> 3;
    const int kc = blockIdx.x & 7;
    const float* W = (w == 0) ? Wq : (w == 1) ? Wk : Wv;
    const int tid = threadIdx.x;
#pragma unroll
    for (int it = 0; it < 8; ++it) {
      const int row = it * 4 + (tid >> 6);
      const int col = (tid & 63) * 4;
      f32x4 v = *(const f32x4*)(W + (size_t)(kc * 32 + row) * DIM + col);
      bf16x4 b;
      b[0] = (short)f2bf(v[0]); b[1] = (short)f2bf(v[1]);
      b[2] = (short)f2bf(v[2]); b[3] = (short)f2bf(v[3]);
      *(bf16x4*)(&WL32[row][col]) = b;
    }
    __syncthreads();
    const int lane = tid & 63;
    const int ww = tid >> 6;
    const int g = lane >> 4, c = lane & 15;
#pragma unroll
    for (int jt = 0; jt < 4; ++jt) {
      const int nt = jt * 4 + ww;
      bf16x8 o;
#pragma unroll
      for (int j = 0; j < 8; ++j)
        o[j] = (short)WL32[g * 8 + j][nt * 16 + c];
      *(bf16x8*)(Wt + (size_t)((w * 16 + nt) * 8 + kc) * 512 + lane * 8) = o;
    }
  } else {
    const int b = blockIdx.x - 24, tid = threadIdx.x;
    float acc = 0.f;
    const float* xp = x + (size_t)b * 32 * DIM + tid;
#pragma unroll
    for (int r = 0; r < 32; ++r) acc += xp[r * DIM];
    partial[b * DIM + tid] = acc;
  }
}

// ---- projections (w = blockIdx.y): x staged once in LDS; W streamed via
// global_load_lds dbuf; epilogue: acc -> LDS tile -> full-line 16B stores ----
__global__ __launch_bounds__(256, 2) void k_proj(const float* __restrict__ x,
    const unsigned short* __restrict__ Wt, unsigned short* __restrict__ Q,
    unsigned short* __restrict__ KS, unsigned short* __restrict__ VS, int n) {
  __shared__ unsigned short XL[64 * 264];     // x-tile; reused as OUT stage (32KB)
  __shared__ unsigned short WL[2][16][512];   // W frags dbuf (32 KB)
  const int rb = blockIdx.x * 64;
  const int w = blockIdx.y;
  const int wave = threadIdx.x >> 6;
  const int lane = threadIdx.x & 63;
  const int g = lane >> 4;
  const int c = lane & 15;

  for (int rr = 0; rr < 16; ++rr) {
    const int r = wave * 16 + rr;
    f32x4 v = *(const f32x4*)(x + (size_t)(rb + r) * DIM + lane * 4);
    u32x2 b;
    b[0] = pack2(v[0], v[1]);
    b[1] = pack2(v[2], v[3]);
    *(u32x2*)(&XL[r * 264 + lane * 4]) = b;
  }
  __syncthreads();

  bf16x8 af[8];
#pragma unroll
  for (int kc = 0; kc < 8; ++kc)
    af[kc] = *(const bf16x8*)(&XL[(wave * 16 + c) * 264 + kc * 32 + g * 8]);

  const unsigned short* Wsrc = Wt + (size_t)w * DIM * DIM + lane * 8;
  auto stagew = [&](int buf, int p) {
#pragma unroll
    for (int q2 = 0; q2 < 4; ++q2) {
      const int m = wave * 4 + q2;
      gload16(Wsrc + (size_t)(p * 16 + m) * 512, &WL[buf][m][0]);
    }
  };

  f32x4 acc[16];
#pragma unroll
  for (int t = 0; t < 16; ++t) acc[t] = (f32x4){0.f, 0.f, 0.f, 0.f};

  stagew(0, 0);
  int buf = 0;
#pragma unroll 1
  for (int p = 0; p < 8; ++p) {
    if (p < 7) {
      stagew(buf ^ 1, p + 1);
      asm volatile("s_waitcnt vmcnt(4)" ::: "memory");
    } else {
      asm volatile("s_waitcnt vmcnt(0)" ::: "memory");
    }
    __builtin_amdgcn_sched_barrier(0);
    __builtin_amdgcn_s_barrier();
    __builtin_amdgcn_sched_barrier(0);
#pragma unroll
    for (int q = 0; q < 2; ++q) {
      const int nt = p * 2 + q;
#pragma unroll
      for (int kc = 0; kc < 8; ++kc) {
        bf16x8 b = *(const bf16x8*)(&WL[buf][q * 8 + kc][lane * 8]);
        acc[nt] = __builtin_amdgcn_mfma_f32_16x16x32_bf16(af[kc], b, acc[nt], 0, 0, 0);
      }
    }
    __builtin_amdgcn_sched_barrier(0);
    __builtin_amdgcn_s_barrier();
    __builtin_amdgcn_sched_barrier(0);
    buf ^= 1;
  }

  // ---- epilogue: scatter acc into XL in the DEST layout, then stream out ----
  if (w == 0) {
#pragma unroll
    for (int nt = 0; nt < 16; ++nt)
#pragma unroll
      for (int r = 0; r < 4; ++r)
        XL[(wave * 16 + 4 * g + r) * 256 + nt * 16 + c] = f2bf(acc[nt][r] * 0.0625f);
  } else if (w == 1) {
    const int lrB = wave * 16 + 4 * g;
#pragma unroll
    for (int nt = 0; nt < 16; ++nt) {
      const int gran = 2 * nt + (c >> 3);
#pragma unroll
      for (int r = 0; r < 4; ++r) {
        const int lr = lrB + r;
        XL[(lr >> 5) * 8192 + gran * 256 + (lr & 31) * 8 + (c & 7)] = f2bf(acc[nt][r]);
      }
    }
  } else {
    const int j0 = wave * 16 + 4 * g;
    const int vbase = (j0 >> 5) * 8192 + ((j0 >> 3) & 3) * 2048 + (j0 & 7);
#pragma unroll
    for (int nt = 0; nt < 16; ++nt) {
      const int col = nt * 16 + c;
      u32x2 pv;
      pv[0] = pack2(acc[nt][0], acc[nt][1]);
      pv[1] = pack2(acc[nt][2], acc[nt][3]);
      *(u32x2*)(&XL[vbase + col * 8]) = pv;
    }
  }
  __syncthreads();
  unsigned short* dstB = (w == 0) ? Q + (size_t)rb * 256
                       : (w == 1) ? KS + (size_t)(rb >> 5) * 8192
                                  : VS + (size_t)(rb >> 5) * 8192;
#pragma unroll
  for (int it = 0; it < 8; ++it)
    *(bf16x8*)(dstB + it * 2048 + threadIdx.x * 8) =
        *(const bf16x8*)(&XL[it * 2048 + threadIdx.x * 8]);
}

// ---- row 0 exact path for fallback: out[0] = mean_n(x) @ Wv ----
__global__ void k_meanB(const float* __restrict__ partial, const float* __restrict__ Wv,
                        float* __restrict__ out, int n) {
  __shared__ float xm[DIM];
  const int tid = threadIdx.x;
  float acc = 0.f;
  const int nb = n / 32;
  for (int b = 0; b < nb; ++b) acc += partial[b * DIM + tid];
  xm[tid] = acc / (float)n;
  __syncthreads();
  float o = 0.f;
  for (int k = 0; k < DIM; ++k) o += xm[k] * Wv[k * DIM + tid];
  out[tid] = o;
}

// ---- fallback flash (KS/VS layouts) ----
__global__ __launch_bounds__(512, 4) void k_flash2(const unsigned short* __restrict__ Q,
    const unsigned short* __restrict__ KS, const unsigned short* __restrict__ VS,
    float* __restrict__ out, int n) {
  __shared__ float so[4][16][257];
  __shared__ float sml[4][2][16];
  __shared__ unsigned short plds[8][16][40];

  const int wave = threadIdx.x >> 6;
  const int lane = threadIdx.x & 63;
  const int g = lane >> 4;
  const int c = lane & 15;
  const int ntiles = n >> 4;
  const int tile = ntiles - 1 - (int)blockIdx.x;
  const int qb = tile << 4;

  bf16x8 qf[8];
  const unsigned short* qp = Q + (size_t)(qb + c) * DIM;
#pragma unroll
  for (int kc = 0; kc < 8; ++kc)
    qf[kc] = *(const bf16x8*)(qp + kc * 32 + g * 8);

  f32x4 o[16];
#pragma unroll
  for (int t = 0; t < 16; ++t) o[t] = (f32x4){0.f, 0.f, 0.f, 0.f};
  float m_r[4] = {-1e30f, -1e30f, -1e30f, -1e30f};
  float l_r[4] = {0.f, 0.f, 0.f, 0.f};

  const int nchunk = ((qb + 14) >> 5) + 1;
  for (int kt = wave; kt < nchunk; kt += 8) {
    const int k0 = kt << 5;
    const unsigned short* kch = KS + (size_t)(k0 >> 5) * 8192;
    f32x4 s0 = {0.f, 0.f, 0.f, 0.f}, s1 = {0.f, 0.f, 0.f, 0.f};
#pragma unroll
    for (int kc = 0; kc < 8; ++kc) {
      bf16x8 kb0 = *(const bf16x8*)(kch + (4 * kc + g) * 256 + c * 8);
      bf16x8 kb1 = *(const bf16x8*)(kch + (4 * kc + g) * 256 + (16 + c) * 8);
      s0 = __builtin_amdgcn_mfma_f32_16x16x32_bf16(qf[kc], kb0, s0, 0, 0, 0);
      s1 = __builtin_amdgcn_mfma_f32_16x16x32_bf16(qf[kc], kb1, s1, 0, 0, 0);
    }
    if (k0 + 31 >= qb) {
#pragma unroll
      for (int r = 0; r < 4; ++r) {
        const int qrow = qb + 4 * g + r;
        if (k0 + c >= qrow)      s0[r] = -1e9f;
        if (k0 + 16 + c >= qrow) s1[r] = -1e9f;
      }
    }
    f32x4 p0, p1;
    float alpha[4];
#pragma unroll
    for (int r = 0; r < 4; ++r) {
      float mx = fmaxf(s0[r], s1[r]);
      mx = fmaxf(mx, __shfl_xor(mx, 1, 64));
      mx = fmaxf(mx, __shfl_xor(mx, 2, 64));
      mx = fmaxf(mx, __shfl_xor(mx, 4, 64));
      mx = fmaxf(mx, __shfl_xor(mx, 8, 64));
      const float mn = fmaxf(m_r[r], mx);
      const float a = __expf(m_r[r] - mn);
      p0[r] = __expf(s0[r] - mn);
      p1[r] = __expf(s1[r] - mn);
      float ls = p0[r] + p1[r];
      ls += __shfl_xor(ls, 1, 64);
      ls += __shfl_xor(ls, 2, 64);
      ls += __shfl_xor(ls, 4, 64);
      ls += __shfl_xor(ls, 8, 64);
      l_r[r] = l_r[r] * a + ls;
      m_r[r] = mn;
      alpha[r] = a;
    }
#pragma unroll
    for (int t = 0; t < 16; ++t) {
      o[t][0] *= alpha[0]; o[t][1] *= alpha[1];
      o[t][2] *= alpha[2]; o[t][3] *= alpha[3];
    }
#pragma unroll
    for (int r = 0; r < 4; ++r) {
      plds[wave][4 * g + r][c]      = f2bf(p0[r]);
      plds[wave][4 * g + r][16 + c] = f2bf(p1[r]);
    }
    asm volatile("s_waitcnt lgkmcnt(0)" ::: "memory");
    const bf16x8 pa = *(const bf16x8*)(&plds[wave][c][8 * g]);
    const unsigned short* vch = VS + (size_t)(k0 >> 5) * 8192 + g * 2048;
#pragma unroll
    for (int t = 0; t < 16; ++t) {
      bf16x8 vb = *(const bf16x8*)(vch + (size_t)(c + 16 * t) * 8);
      o[t] = __builtin_amdgcn_mfma_f32_16x16x32_bf16(pa, vb, o[t], 0, 0, 0);
    }
  }

  auto write_slot = [&](int s) {
#pragma unroll
    for (int r = 0; r < 4; ++r) {
      const int row = 4 * g + r;
#pragma unroll
      for (int t = 0; t < 16; ++t) so[s][row][t * 16 + c] = o[t][r];
      if (c == 0) { sml[s][0][row] = m_r[r]; sml[s][1][row] = l_r[r]; }
    }
  };
  auto merge_slot = [&](int s) {
    float aa[4], ab[4];
#pragma unroll
    for (int r = 0; r < 4; ++r) {
      const int row = 4 * g + r;
      const float mb = sml[s][0][row], lb = sml[s][1][row];
      const float ms = fmaxf(m_r[r], mb);
      aa[r] = __expf(m_r[r] - ms);
      ab[r] = __expf(mb - ms);
      l_r[r] = l_r[r] * aa[r] + lb * ab[r];
      m_r[r] = ms;
    }
#pragma unroll
    for (int t = 0; t < 16; ++t)
#pragma unroll
      for (int r = 0; r < 4; ++r)
        o[t][r] = o[t][r] * aa[r] + so[s][4 * g + r][t * 16 + c] * ab[r];
  };

  __syncthreads();
  if (wave >= 4) write_slot(wave - 4);
  __syncthreads();
  if (wave < 4) merge_slot(wave);
  __syncthreads();
  if (wave == 2 || wave == 3) write_slot(wave - 2);
  __syncthreads();
  if (wave < 2) merge_slot(wave);
  __syncthreads();
  if (wave == 1) write_slot(0);
  __syncthreads();
  if (wave == 0) {
    merge_slot(0);
#pragma unroll
    for (int r = 0; r < 4; ++r) {
      const int qrow = qb + 4 * g + r;
      if (qrow == 0) continue;
      const float inv = 1.0f / l_r[r];
#pragma unroll
      for (int t = 0; t < 16; ++t)
        out[(size_t)qrow * DIM + t * 16 + c] = o[t][r] * inv;
    }
  }
}

// ---- main flash: 32x32x16, swapped QK^T; permlane32_swap P-transpose;
// balanced slots (nsplit = ceil((4t+4)/CH), nslots <= 512) ----
template <int CH>
__global__ __launch_bounds__(256, 2) void k_flash8(const unsigned short* __restrict__ Q,
    const unsigned short* __restrict__ KS, const unsigned short* __restrict__ VS,
    unsigned short* __restrict__ po, float* __restrict__ pl, int n) {
  __shared__ unsigned short KL[2][32 * 32 * 8];   // [granule d/8][key][8]
  __shared__ unsigned short VL[2][4 * 256 * 8];   // [granule key/8][d][8]

  const int wave = threadIdx.x >> 6;
  const int lane = threadIdx.x & 63;
  const int r32 = lane & 31;
  const int h   = lane >> 5;

  const int bid = (int)(gridDim.x - 1 - blockIdx.x);   // heaviest slots first
  int t = 0, cacc = 0;
  for (;;) {
    const int ns = (4 * t + 4 + CH - 1) / CH;
    if (cacc + ns > bid) break;
    cacc += ns; ++t;
  }
  const int sp = bid - cacc;
  const int nsplit = (4 * t + 4 + CH - 1) / CH;
  const int qb = t << 7;
  const int qw = qb + (wave << 5);
  const int nch = 4 * t + 4;
  const int qrow_me = qw + r32;

  bf16x8 qf[16];
  const unsigned short* qp = Q + (size_t)qrow_me * DIM + h * 8;
#pragma unroll
  for (int kc = 0; kc < 16; ++kc)
    qf[kc] = *(const bf16x8*)(qp + kc * 16);

  f32x16 o[8];
#pragma unroll
  for (int dt = 0; dt < 8; ++dt)
#pragma unroll
    for (int r = 0; r < 16; ++r) o[dt][r] = 0.f;
  float lac = 0.f;

  const unsigned short* Ksrc = KS + (size_t)lane * 8;
  const unsigned short* Vsrc = VS + (size_t)lane * 8;

  auto stage = [&](int buf, int k0) {
    const size_t cb = (size_t)(k0 >> 5) * 8192;
#pragma unroll
    for (int jj = 0; jj < 4; ++jj)
      gload16(Ksrc + cb + (8 * wave + 2 * jj) * 256,
              &KL[buf][(8 * wave + 2 * jj) * 256]);
#pragma unroll
    for (int jj = 0; jj < 4; ++jj)
      gload16(Vsrc + cb + wave * 2048 + jj * 512,
              &VL[buf][(wave * 256 + jj * 64) * 8]);
  };

  int ci = sp;
  stage(0, ci << 5);
  int buf = 0;
  for (;;) {
    const int k0 = ci << 5;
    const int cin = ci + nsplit;
    const bool more = (cin < nch);
    if (more) {
      stage(buf ^ 1, cin << 5);
      asm volatile("s_waitcnt vmcnt(8)" ::: "memory");
    } else {
      asm volatile("s_waitcnt vmcnt(0)" ::: "memory");
    }
    __builtin_amdgcn_sched_barrier(0);
    __builtin_amdgcn_s_barrier();
    __builtin_amdgcn_sched_barrier(0);

    if (k0 <= qw + 30) {
      f32x16 sa, sb;
#pragma unroll
      for (int r = 0; r < 16; ++r) { sa[r] = 0.f; sb[r] = 0.f; }
      __builtin_amdgcn_s_setprio(1);
#pragma unroll
      for (int kc = 0; kc < 8; ++kc) {
        bf16x8 kbA = *(const bf16x8*)(&KL[buf][((2 * kc + h) * 32 + r32) * 8]);
        bf16x8 kbB = *(const bf16x8*)(&KL[buf][((2 * kc + 16 + h) * 32 + r32) * 8]);
        sa = __builtin_amdgcn_mfma_f32_32x32x16_bf16(kbA, qf[kc], sa, 0, 0, 0);
        sb = __builtin_amdgcn_mfma_f32_32x32x16_bf16(kbB, qf[kc + 8], sb, 0, 0, 0);
      }
      __builtin_amdgcn_s_setprio(0);
      f32x16 s = sa + sb;
      if (k0 + 31 >= qw) {
#pragma unroll
        for (int r = 0; r < 16; ++r) {
          const int key = k0 + (r & 3) + 8 * (r >> 2) + 4 * h;
          if (key >= qrow_me) s[r] = -1e9f;
        }
      }
      uint32_t pk0l, pk0h, pk1l, pk1h, pk2l, pk2h, pk3l, pk3h;
      {
        float p0, p1, p2, p3;
        p0 = __expf(s[0] - 16.f);  p1 = __expf(s[1] - 16.f);
        p2 = __expf(s[2] - 16.f);  p3 = __expf(s[3] - 16.f);
        lac += (p0 + p1) + (p2 + p3);
        pk0l = pack2(p0, p1); pk0h = pack2(p2, p3);
        p0 = __expf(s[4] - 16.f);  p1 = __expf(s[5] - 16.f);
        p2 = __expf(s[6] - 16.f);  p3 = __expf(s[7] - 16.f);
        lac += (p0 + p1) + (p2 + p3);
        pk1l = pack2(p0, p1); pk1h = pack2(p2, p3);
        p0 = __expf(s[8] - 16.f);  p1 = __expf(s[9] - 16.f);
        p2 = __expf(s[10] - 16.f); p3 = __expf(s[11] - 16.f);
        lac += (p0 + p1) + (p2 + p3);
        pk2l = pack2(p0, p1); pk2h = pack2(p2, p3);
        p0 = __expf(s[12] - 16.f); p1 = __expf(s[13] - 16.f);
        p2 = __expf(s[14] - 16.f); p3 = __expf(s[15] - 16.f);
        lac += (p0 + p1) + (p2 + p3);
        pk3l = pack2(p0, p1); pk3h = pack2(p2, p3);
      }
      {
        uint32_t a0 = pk0l, b0 = pk1l, a1 = pk0h, b1 = pk1h;
        asm volatile("v_permlane32_swap_b32 %0, %1" : "+v"(a0), "+v"(b0));
        asm volatile("v_permlane32_swap_b32 %0, %1" : "+v"(a1), "+v"(b1));
        union { bf16x8 v; uint32_t u[4]; } pa;
        pa.u[0] = a0; pa.u[1] = a1; pa.u[2] = b0; pa.u[3] = b1;
        __builtin_amdgcn_s_setprio(1);
#pragma unroll
        for (int dt = 0; dt < 8; ++dt) {
          bf16x8 vb = *(const bf16x8*)(&VL[buf][(h * 256 + dt * 32 + r32) * 8]);
          o[dt] = __builtin_amdgcn_mfma_f32_32x32x16_bf16(pa.v, vb, o[dt], 0, 0, 0);
        }
        __builtin_amdgcn_s_setprio(0);
      }
      {
        uint32_t a0 = pk2l, b0 = pk3l, a1 = pk2h, b1 = pk3h;
        asm volatile("v_permlane32_swap_b32 %0, %1" : "+v"(a0), "+v"(b0));
        asm volatile("v_permlane32_swap_b32 %0, %1" : "+v"(a1), "+v"(b1));
        union { bf16x8 v; uint32_t u[4]; } pa;
        pa.u[0] = a0; pa.u[1] = a1; pa.u[2] = b0; pa.u[3] = b1;
        __builtin_amdgcn_s_setprio(1);
#pragma unroll
        for (int dt = 0; dt < 8; ++dt) {
          bf16x8 vb = *(const bf16x8*)(&VL[buf][((2 + h) * 256 + dt * 32 + r32) * 8]);
          o[dt] = __builtin_amdgcn_mfma_f32_32x32x16_bf16(pa.v, vb, o[dt], 0, 0, 0);
        }
        __builtin_amdgcn_s_setprio(0);
      }
    }

    __builtin_amdgcn_sched_barrier(0);
    __builtin_amdgcn_s_barrier();
    __builtin_amdgcn_sched_barrier(0);
    if (!more) break;
    buf ^= 1;
    ci = cin;
  }

  const float lacF = lac + __shfl_xor(lac, 32, 64);
  unsigned short* pow = po + ((size_t)bid * 128 + (wave << 5)) * DIM;
  float* plw = pl + (size_t)bid * 128 + (wave << 5);
  if (h == 0) plw[r32] = lacF;
#pragma unroll
  for (int r = 0; r < 16; ++r) {
    const int srow = (r & 3) + 8 * (r >> 2) + 4 * h;
#pragma unroll
    for (int dt = 0; dt < 8; ++dt)
      pow[(size_t)srow * DIM + dt * 32 + r32] = f2bf(o[dt][r]);
  }
}

// ---- combine: straight sum over a tile's splits, normalize; block 0 row 0 ----
template <int CH>
__global__ __launch_bounds__(256) void k_comb(const unsigned short* __restrict__ po,
    const float* __restrict__ pl, const float* __restrict__ partial,
    const float* __restrict__ Wv, float* __restrict__ out, int n) {
  const int row = blockIdx.x * 16 + (threadIdx.x >> 4);
  const int c0 = (threadIdx.x & 15) * 16;
  const int t = row >> 7;
  int cumt = 0;
  for (int u = 0; u < t; ++u) cumt += (4 * u + 4 + CH - 1) / CH;
  const int ns = (4 * t + 4 + CH - 1) / CH;
  const int lr = row & 127;

  float acc[16];
#pragma unroll
  for (int j = 0; j < 16; ++j) acc[j] = 0.f;
  float lsum = 0.f;
  for (int s = 0; s < ns; ++s) {
    lsum += pl[(size_t)(cumt + s) * 128 + lr];
    const unsigned short* pp = po + ((size_t)(cumt + s) * 128 + lr) * DIM + c0;
    bf16x8 v0 = *(const bf16x8*)(pp);
    bf16x8 v1 = *(const bf16x8*)(pp + 8);
#pragma unroll
    for (int j = 0; j < 8; ++j) {
      union { float f; uint32_t u; } cv0, cv1;
      cv0.u = ((uint32_t)(unsigned short)v0[j]) << 16;
      cv1.u = ((uint32_t)(unsigned short)v1[j]) << 16;
      acc[j]     += cv0.f;
      acc[8 + j] += cv1.f;
    }
  }
  const float inv = (lsum > 0.f) ? 1.0f / lsum : 0.f;
#pragma unroll
  for (int j = 0; j < 16; ++j)
    out[(size_t)row * DIM + c0 + j] = acc[j] * inv;

  if (blockIdx.x == 0) {   // exact row 0: mean(x) @ Wv
    __shared__ float xm[DIM];
    const int tid = threadIdx.x;
    float s = 0.f;
    const int nb = n / 32;
    for (int b = 0; b < nb; ++b) s += partial[b * DIM + tid];
    xm[tid] = s / (float)n;
    __syncthreads();
    float oo = 0.f;
    for (int k = 0; k < DIM; ++k) oo += xm[k] * Wv[k * DIM + tid];
    out[tid] = oo;
  }
}

extern "C" void kernel_launch(void* const* d_in, const int* in_sizes, int n_in,
                              void* d_out, int out_size, void* d_ws, size_t ws_size,
                              hipStream_t stream) {
  const float* x  = (const float*)d_in[0];
  const float* Wq = (const float*)d_in[1];
  const float* Wk = (const float*)d_in[2];
  const float* Wv = (const float*)d_in[3];
  float* out = (float*)d_out;
  const int n = in_sizes[0] / DIM;
  const int T = n >> 7;

  char* ws = (char*)d_ws;
  const size_t wt_bytes  = (size_t)3 * DIM * DIM * 2;
  const size_t mat_bytes = (size_t)n * DIM * 2;
  const size_t par_bytes = (size_t)(n / 32) * DIM * 4;
  const size_t base = wt_bytes + 3 * mat_bytes + par_bytes;

  unsigned short* Wt = (unsigned short*)(ws);
  unsigned short* Q  = (unsigned short*)(ws + wt_bytes);
  unsigned short* KS = (unsigned short*)(ws + wt_bytes + mat_bytes);
  unsigned short* VS = (unsigned short*)(ws + wt_bytes + 2 * mat_bytes);
  float* partial     = (float*)(ws + wt_bytes + 3 * mat_bytes);

  auto slots_for = [&](int CH) {
    int s = 0;
    for (int t = 0; t < T; ++t) s += (4 * t + 4 + CH - 1) / CH;
    return s;
  };
  const int ns18 = slots_for(18);
  const int ns36 = slots_for(36);
  const size_t need18 = base + (size_t)ns18 * 128 * 4 + (size_t)ns18 * 128 * DIM * 2;
  const size_t need36 = base + (size_t)ns36 * 128 * 4 + (size_t)ns36 * 128 * DIM * 2;
  int mode = 0, nslots = 0;
  if (ws_size >= need18)      { mode = 18; nslots = ns18; }
  else if (ws_size >= need36) { mode = 36; nslots = ns36; }
  float* pl          = (float*)(ws + base);
  unsigned short* po = (unsigned short*)(ws + base + (size_t)nslots * 128 * 4);

  hipLaunchKernelGGL(k_prep, dim3(24 + n / 32), dim3(256), 0, stream,
                     Wq, Wk, Wv, Wt, x, partial, n);
  hipLaunchKernelGGL(k_proj, dim3(n / 64, 3), dim3(256), 0, stream, x, Wt, Q, KS, VS, n);
  if (mode == 18) {
    hipLaunchKernelGGL((k_flash8<18>), dim3(nslots), dim3(256), 0, stream,
                       Q, KS, VS, po, pl, n);
    hipLaunchKernelGGL((k_comb<18>), dim3(n / 16), dim3(256), 0, stream,
                       po, pl, partial, Wv, out, n);
  } else if (mode == 36) {
    hipLaunchKernelGGL((k_flash8<36>), dim3(nslots), dim3(256), 0, stream,
                       Q, KS, VS, po, pl, n);
    hipLaunchKernelGGL((k_comb<36>), dim3(n / 16), dim3(256), 0, stream,
                       po, pl, partial, Wv, out, n);
  } else {
    hipLaunchKernelGGL(k_flash2, dim3(n / 16), dim3(512), 0, stream, Q, KS, VS, out, n);
    hipLaunchKernelGGL(k_meanB, dim3(1), dim3(256), 0, stream, partial, Wv, out, n);
  }
}

// Round 17
// 87.910 us; speedup vs baseline: 1.6711x; 1.6711x over previous
//
#include <hip/hip_runtime.h>
#include <hip/hip_bf16.h>
#include <stdint.h>

#define DIM 256

typedef float f32x4  __attribute__((ext_vector_type(4)));
typedef float f32x16 __attribute__((ext_vector_type(16)));
typedef short bf16x8 __attribute__((ext_vector_type(8)));
typedef short bf16x4 __attribute__((ext_vector_type(4)));
typedef unsigned int u32x2 __attribute__((ext_vector_type(2)));

__device__ __forceinline__ unsigned short f2bf(float f) {
  union { float f; uint32_t u; } v; v.f = f;
  uint32_t u = v.u;
  u += 0x7FFFu + ((u >> 16) & 1u);   // round-to-nearest-even
  return (unsigned short)(u >> 16);
}

// packed f32x2 -> bf16x2 (RNE), single instruction
__device__ __forceinline__ uint32_t pack2(float lo, float hi) {
  uint32_t r;
  asm("v_cvt_pk_bf16_f32 %0, %1, %2" : "=v"(r) : "v"(lo), "v"(hi));
  return r;
}

// async global->LDS, 16B per lane; LDS dest = wave-uniform base (+ lane*16 by HW)
__device__ __forceinline__ void gload16(const unsigned short* g, unsigned short* l) {
  __builtin_amdgcn_global_load_lds(
      (const __attribute__((address_space(1))) unsigned int*)g,
      (__attribute__((address_space(3))) unsigned int*)l, 16, 0, 0);
}

// ---- prep: W -> MFMA-fragment layout WF[(w*16+nt)*8+kc][512] via LDS tile
//      (blocks 0..23); x column partial sums, 128 rows/block (blocks 24..) ----
__global__ __launch_bounds__(256) void k_prep(const float* __restrict__ Wq,
    const float* __restrict__ Wk, const float* __restrict__ Wv,
    unsigned short* __restrict__ Wt, const float* __restrict__ x,
    float* __restrict__ partial, int n) {
  __shared__ unsigned short WL32[32][264];
  if (blockIdx.x < 24) {
    const int w  = blockIdx.x >> 3;
    const int kc = blockIdx.x & 7;
    const float* W = (w == 0) ? Wq : (w == 1) ? Wk : Wv;
    const int tid = threadIdx.x;
#pragma unroll
    for (int it = 0; it < 8; ++it) {
      const int row = it * 4 + (tid >> 6);
      const int col = (tid & 63) * 4;
      f32x4 v = *(const f32x4*)(W + (size_t)(kc * 32 + row) * DIM + col);
      bf16x4 b;
      b[0] = (short)f2bf(v[0]); b[1] = (short)f2bf(v[1]);
      b[2] = (short)f2bf(v[2]); b[3] = (short)f2bf(v[3]);
      *(bf16x4*)(&WL32[row][col]) = b;
    }
    __syncthreads();
    const int lane = tid & 63;
    const int ww = tid >> 6;
    const int g = lane >> 4, c = lane & 15;
#pragma unroll
    for (int jt = 0; jt < 4; ++jt) {
      const int nt = jt * 4 + ww;
      bf16x8 o;
#pragma unroll
      for (int j = 0; j < 8; ++j)
        o[j] = (short)WL32[g * 8 + j][nt * 16 + c];
      *(bf16x8*)(Wt + (size_t)((w * 16 + nt) * 8 + kc) * 512 + lane * 8) = o;
    }
  } else {
    const int b = blockIdx.x - 24, tid = threadIdx.x;
    float acc = 0.f;
    const float* xp = x + (size_t)b * 128 * DIM + tid;
#pragma unroll 8
    for (int r = 0; r < 128; ++r) acc += xp[r * DIM];
    partial[b * DIM + tid] = acc;
  }
}

// ---- projections (w = blockIdx.y): x staged once in LDS; W streamed via
// global_load_lds dbuf; epilogue: acc -> LDS tile -> full-line 16B stores ----
__global__ __launch_bounds__(256, 2) void k_proj(const float* __restrict__ x,
    const unsigned short* __restrict__ Wt, unsigned short* __restrict__ Q,
    unsigned short* __restrict__ KS, unsigned short* __restrict__ VS, int n) {
  __shared__ unsigned short XL[64 * 264];     // x-tile; reused as OUT stage (32KB)
  __shared__ unsigned short WL[2][16][512];   // W frags dbuf (32 KB)
  const int rb = blockIdx.x * 64;
  const int w = blockIdx.y;
  const int wave = threadIdx.x >> 6;
  const int lane = threadIdx.x & 63;
  const int g = lane >> 4;
  const int c = lane & 15;

  for (int rr = 0; rr < 16; ++rr) {
    const int r = wave * 16 + rr;
    f32x4 v = *(const f32x4*)(x + (size_t)(rb + r) * DIM + lane * 4);
    u32x2 b;
    b[0] = pack2(v[0], v[1]);
    b[1] = pack2(v[2], v[3]);
    *(u32x2*)(&XL[r * 264 + lane * 4]) = b;
  }
  __syncthreads();

  bf16x8 af[8];
#pragma unroll
  for (int kc = 0; kc < 8; ++kc)
    af[kc] = *(const bf16x8*)(&XL[(wave * 16 + c) * 264 + kc * 32 + g * 8]);

  const unsigned short* Wsrc = Wt + (size_t)w * DIM * DIM + lane * 8;
  auto stagew = [&](int buf, int p) {
#pragma unroll
    for (int q2 = 0; q2 < 4; ++q2) {
      const int m = wave * 4 + q2;
      gload16(Wsrc + (size_t)(p * 16 + m) * 512, &WL[buf][m][0]);
    }
  };

  f32x4 acc[16];
#pragma unroll
  for (int t = 0; t < 16; ++t) acc[t] = (f32x4){0.f, 0.f, 0.f, 0.f};

  stagew(0, 0);
  int buf = 0;
#pragma unroll 1
  for (int p = 0; p < 8; ++p) {
    if (p < 7) {
      stagew(buf ^ 1, p + 1);
      asm volatile("s_waitcnt vmcnt(4)" ::: "memory");
    } else {
      asm volatile("s_waitcnt vmcnt(0)" ::: "memory");
    }
    __builtin_amdgcn_sched_barrier(0);
    __builtin_amdgcn_s_barrier();
    __builtin_amdgcn_sched_barrier(0);
#pragma unroll
    for (int q = 0; q < 2; ++q) {
      const int nt = p * 2 + q;
#pragma unroll
      for (int kc = 0; kc < 8; ++kc) {
        bf16x8 b = *(const bf16x8*)(&WL[buf][q * 8 + kc][lane * 8]);
        acc[nt] = __builtin_amdgcn_mfma_f32_16x16x32_bf16(af[kc], b, acc[nt], 0, 0, 0);
      }
    }
    __builtin_amdgcn_sched_barrier(0);
    __builtin_amdgcn_s_barrier();
    __builtin_amdgcn_sched_barrier(0);
    buf ^= 1;
  }

  // ---- epilogue: scatter acc into XL in the DEST layout, then stream out ----
  if (w == 0) {
#pragma unroll
    for (int nt = 0; nt < 16; ++nt)
#pragma unroll
      for (int r = 0; r < 4; ++r)
        XL[(wave * 16 + 4 * g + r) * 256 + nt * 16 + c] = f2bf(acc[nt][r] * 0.0625f);
  } else if (w == 1) {
    const int lrB = wave * 16 + 4 * g;
#pragma unroll
    for (int nt = 0; nt < 16; ++nt) {
      const int gran = 2 * nt + (c >> 3);
#pragma unroll
      for (int r = 0; r < 4; ++r) {
        const int lr = lrB + r;
        XL[(lr >> 5) * 8192 + gran * 256 + (lr & 31) * 8 + (c & 7)] = f2bf(acc[nt][r]);
      }
    }
  } else {
    const int j0 = wave * 16 + 4 * g;
    const int vbase = (j0 >> 5) * 8192 + ((j0 >> 3) & 3) * 2048 + (j0 & 7);
#pragma unroll
    for (int nt = 0; nt < 16; ++nt) {
      const int col = nt * 16 + c;
      u32x2 pv;
      pv[0] = pack2(acc[nt][0], acc[nt][1]);
      pv[1] = pack2(acc[nt][2], acc[nt][3]);
      *(u32x2*)(&XL[vbase + col * 8]) = pv;
    }
  }
  __syncthreads();
  unsigned short* dstB = (w == 0) ? Q + (size_t)rb * 256
                       : (w == 1) ? KS + (size_t)(rb >> 5) * 8192
                                  : VS + (size_t)(rb >> 5) * 8192;
#pragma unroll
  for (int it = 0; it < 8; ++it)
    *(bf16x8*)(dstB + it * 2048 + threadIdx.x * 8) =
        *(const bf16x8*)(&XL[it * 2048 + threadIdx.x * 8]);
}

// ---- row 0 exact path for fallback: out[0] = mean_n(x) @ Wv ----
__global__ void k_meanB(const float* __restrict__ partial, const float* __restrict__ Wv,
                        float* __restrict__ out, int n) {
  __shared__ float xm[DIM];
  const int tid = threadIdx.x;
  float acc = 0.f;
  const int nb = n / 128;
  for (int b = 0; b < nb; ++b) acc += partial[b * DIM + tid];
  xm[tid] = acc / (float)n;
  __syncthreads();
  float o = 0.f;
  for (int k = 0; k < DIM; ++k) o += xm[k] * Wv[k * DIM + tid];
  out[tid] = o;
}

// ---- fallback flash (KS/VS layouts) ----
__global__ __launch_bounds__(512, 4) void k_flash2(const unsigned short* __restrict__ Q,
    const unsigned short* __restrict__ KS, const unsigned short* __restrict__ VS,
    float* __restrict__ out, int n) {
  __shared__ float so[4][16][257];
  __shared__ float sml[4][2][16];
  __shared__ unsigned short plds[8][16][40];

  const int wave = threadIdx.x >> 6;
  const int lane = threadIdx.x & 63;
  const int g = lane >> 4;
  const int c = lane & 15;
  const int ntiles = n >> 4;
  const int tile = ntiles - 1 - (int)blockIdx.x;
  const int qb = tile << 4;

  bf16x8 qf[8];
  const unsigned short* qp = Q + (size_t)(qb + c) * DIM;
#pragma unroll
  for (int kc = 0; kc < 8; ++kc)
    qf[kc] = *(const bf16x8*)(qp + kc * 32 + g * 8);

  f32x4 o[16];
#pragma unroll
  for (int t = 0; t < 16; ++t) o[t] = (f32x4){0.f, 0.f, 0.f, 0.f};
  float m_r[4] = {-1e30f, -1e30f, -1e30f, -1e30f};
  float l_r[4] = {0.f, 0.f, 0.f, 0.f};

  const int nchunk = ((qb + 14) >> 5) + 1;
  for (int kt = wave; kt < nchunk; kt += 8) {
    const int k0 = kt << 5;
    const unsigned short* kch = KS + (size_t)(k0 >> 5) * 8192;
    f32x4 s0 = {0.f, 0.f, 0.f, 0.f}, s1 = {0.f, 0.f, 0.f, 0.f};
#pragma unroll
    for (int kc = 0; kc < 8; ++kc) {
      bf16x8 kb0 = *(const bf16x8*)(kch + (4 * kc + g) * 256 + c * 8);
      bf16x8 kb1 = *(const bf16x8*)(kch + (4 * kc + g) * 256 + (16 + c) * 8);
      s0 = __builtin_amdgcn_mfma_f32_16x16x32_bf16(qf[kc], kb0, s0, 0, 0, 0);
      s1 = __builtin_amdgcn_mfma_f32_16x16x32_bf16(qf[kc], kb1, s1, 0, 0, 0);
    }
    if (k0 + 31 >= qb) {
#pragma unroll
      for (int r = 0; r < 4; ++r) {
        const int qrow = qb + 4 * g + r;
        if (k0 + c >= qrow)      s0[r] = -1e9f;
        if (k0 + 16 + c >= qrow) s1[r] = -1e9f;
      }
    }
    f32x4 p0, p1;
    float alpha[4];
#pragma unroll
    for (int r = 0; r < 4; ++r) {
      float mx = fmaxf(s0[r], s1[r]);
      mx = fmaxf(mx, __shfl_xor(mx, 1, 64));
      mx = fmaxf(mx, __shfl_xor(mx, 2, 64));
      mx = fmaxf(mx, __shfl_xor(mx, 4, 64));
      mx = fmaxf(mx, __shfl_xor(mx, 8, 64));
      const float mn = fmaxf(m_r[r], mx);
      const float a = __expf(m_r[r] - mn);
      p0[r] = __expf(s0[r] - mn);
      p1[r] = __expf(s1[r] - mn);
      float ls = p0[r] + p1[r];
      ls += __shfl_xor(ls, 1, 64);
      ls += __shfl_xor(ls, 2, 64);
      ls += __shfl_xor(ls, 4, 64);
      ls += __shfl_xor(ls, 8, 64);
      l_r[r] = l_r[r] * a + ls;
      m_r[r] = mn;
      alpha[r] = a;
    }
#pragma unroll
    for (int t = 0; t < 16; ++t) {
      o[t][0] *= alpha[0]; o[t][1] *= alpha[1];
      o[t][2] *= alpha[2]; o[t][3] *= alpha[3];
    }
#pragma unroll
    for (int r = 0; r < 4; ++r) {
      plds[wave][4 * g + r][c]      = f2bf(p0[r]);
      plds[wave][4 * g + r][16 + c] = f2bf(p1[r]);
    }
    asm volatile("s_waitcnt lgkmcnt(0)" ::: "memory");
    const bf16x8 pa = *(const bf16x8*)(&plds[wave][c][8 * g]);
    const unsigned short* vch = VS + (size_t)(k0 >> 5) * 8192 + g * 2048;
#pragma unroll
    for (int t = 0; t < 16; ++t) {
      bf16x8 vb = *(const bf16x8*)(vch + (size_t)(c + 16 * t) * 8);
      o[t] = __builtin_amdgcn_mfma_f32_16x16x32_bf16(pa, vb, o[t], 0, 0, 0);
    }
  }

  auto write_slot = [&](int s) {
#pragma unroll
    for (int r = 0; r < 4; ++r) {
      const int row = 4 * g + r;
#pragma unroll
      for (int t = 0; t < 16; ++t) so[s][row][t * 16 + c] = o[t][r];
      if (c == 0) { sml[s][0][row] = m_r[r]; sml[s][1][row] = l_r[r]; }
    }
  };
  auto merge_slot = [&](int s) {
    float aa[4], ab[4];
#pragma unroll
    for (int r = 0; r < 4; ++r) {
      const int row = 4 * g + r;
      const float mb = sml[s][0][row], lb = sml[s][1][row];
      const float ms = fmaxf(m_r[r], mb);
      aa[r] = __expf(m_r[r] - ms);
      ab[r] = __expf(mb - ms);
      l_r[r] = l_r[r] * aa[r] + lb * ab[r];
      m_r[r] = ms;
    }
#pragma unroll
    for (int t = 0; t < 16; ++t)
#pragma unroll
      for (int r = 0; r < 4; ++r)
        o[t][r] = o[t][r] * aa[r] + so[s][4 * g + r][t * 16 + c] * ab[r];
  };

  __syncthreads();
  if (wave >= 4) write_slot(wave - 4);
  __syncthreads();
  if (wave < 4) merge_slot(wave);
  __syncthreads();
  if (wave == 2 || wave == 3) write_slot(wave - 2);
  __syncthreads();
  if (wave < 2) merge_slot(wave);
  __syncthreads();
  if (wave == 1) write_slot(0);
  __syncthreads();
  if (wave == 0) {
    merge_slot(0);
#pragma unroll
    for (int r = 0; r < 4; ++r) {
      const int qrow = qb + 4 * g + r;
      if (qrow == 0) continue;
      const float inv = 1.0f / l_r[r];
#pragma unroll
      for (int t = 0; t < 16; ++t)
        out[(size_t)qrow * DIM + t * 16 + c] = o[t][r] * inv;
    }
  }
}

// ---- main flash: 32x32x16, swapped QK^T; permlane32_swap P-transpose;
// balanced slots (nsplit = ceil((4t+4)/CH), nslots <= 512) ----
template <int CH>
__global__ __launch_bounds__(256, 2) void k_flash8(const unsigned short* __restrict__ Q,
    const unsigned short* __restrict__ KS, const unsigned short* __restrict__ VS,
    unsigned short* __restrict__ po, float* __restrict__ pl, int n) {
  __shared__ unsigned short KL[2][32 * 32 * 8];   // [granule d/8][key][8]
  __shared__ unsigned short VL[2][4 * 256 * 8];   // [granule key/8][d][8]

  const int wave = threadIdx.x >> 6;
  const int lane = threadIdx.x & 63;
  const int r32 = lane & 31;
  const int h   = lane >> 5;

  const int bid = (int)(gridDim.x - 1 - blockIdx.x);   // heaviest slots first
  int t = 0, cacc = 0;
  for (;;) {
    const int ns = (4 * t + 4 + CH - 1) / CH;
    if (cacc + ns > bid) break;
    cacc += ns; ++t;
  }
  const int sp = bid - cacc;
  const int nsplit = (4 * t + 4 + CH - 1) / CH;
  const int qb = t << 7;
  const int qw = qb + (wave << 5);
  const int nch = 4 * t + 4;
  const int qrow_me = qw + r32;

  bf16x8 qf[16];
  const unsigned short* qp = Q + (size_t)qrow_me * DIM + h * 8;
#pragma unroll
  for (int kc = 0; kc < 16; ++kc)
    qf[kc] = *(const bf16x8*)(qp + kc * 16);

  f32x16 o[8];
#pragma unroll
  for (int dt = 0; dt < 8; ++dt)
#pragma unroll
    for (int r = 0; r < 16; ++r) o[dt][r] = 0.f;
  float lac = 0.f;

  const unsigned short* Ksrc = KS + (size_t)lane * 8;
  const unsigned short* Vsrc = VS + (size_t)lane * 8;

  auto stage = [&](int buf, int k0) {
    const size_t cb = (size_t)(k0 >> 5) * 8192;
#pragma unroll
    for (int jj = 0; jj < 4; ++jj)
      gload16(Ksrc + cb + (8 * wave + 2 * jj) * 256,
              &KL[buf][(8 * wave + 2 * jj) * 256]);
#pragma unroll
    for (int jj = 0; jj < 4; ++jj)
      gload16(Vsrc + cb + wave * 2048 + jj * 512,
              &VL[buf][(wave * 256 + jj * 64) * 8]);
  };

  int ci = sp;
  stage(0, ci << 5);
  int buf = 0;
  for (;;) {
    const int k0 = ci << 5;
    const int cin = ci + nsplit;
    const bool more = (cin < nch);
    if (more) {
      stage(buf ^ 1, cin << 5);
      asm volatile("s_waitcnt vmcnt(8)" ::: "memory");
    } else {
      asm volatile("s_waitcnt vmcnt(0)" ::: "memory");
    }
    __builtin_amdgcn_sched_barrier(0);
    __builtin_amdgcn_s_barrier();
    __builtin_amdgcn_sched_barrier(0);

    if (k0 <= qw + 30) {
      f32x16 sa, sb;
#pragma unroll
      for (int r = 0; r < 16; ++r) { sa[r] = 0.f; sb[r] = 0.f; }
      __builtin_amdgcn_s_setprio(1);
#pragma unroll
      for (int kc = 0; kc < 8; ++kc) {
        bf16x8 kbA = *(const bf16x8*)(&KL[buf][((2 * kc + h) * 32 + r32) * 8]);
        bf16x8 kbB = *(const bf16x8*)(&KL[buf][((2 * kc + 16 + h) * 32 + r32) * 8]);
        sa = __builtin_amdgcn_mfma_f32_32x32x16_bf16(kbA, qf[kc], sa, 0, 0, 0);
        sb = __builtin_amdgcn_mfma_f32_32x32x16_bf16(kbB, qf[kc + 8], sb, 0, 0, 0);
      }
      __builtin_amdgcn_s_setprio(0);
      f32x16 s = sa + sb;
      if (k0 + 31 >= qw) {
#pragma unroll
        for (int r = 0; r < 16; ++r) {
          const int key = k0 + (r & 3) + 8 * (r >> 2) + 4 * h;
          if (key >= qrow_me) s[r] = -1e9f;
        }
      }
      uint32_t pk0l, pk0h, pk1l, pk1h, pk2l, pk2h, pk3l, pk3h;
      {
        float p0, p1, p2, p3;
        p0 = __expf(s[0] - 16.f);  p1 = __expf(s[1] - 16.f);
        p2 = __expf(s[2] - 16.f);  p3 = __expf(s[3] - 16.f);
        lac += (p0 + p1) + (p2 + p3);
        pk0l = pack2(p0, p1); pk0h = pack2(p2, p3);
        p0 = __expf(s[4] - 16.f);  p1 = __expf(s[5] - 16.f);
        p2 = __expf(s[6] - 16.f);  p3 = __expf(s[7] - 16.f);
        lac += (p0 + p1) + (p2 + p3);
        pk1l = pack2(p0, p1); pk1h = pack2(p2, p3);
        p0 = __expf(s[8] - 16.f);  p1 = __expf(s[9] - 16.f);
        p2 = __expf(s[10] - 16.f); p3 = __expf(s[11] - 16.f);
        lac += (p0 + p1) + (p2 + p3);
        pk2l = pack2(p0, p1); pk2h = pack2(p2, p3);
        p0 = __expf(s[12] - 16.f); p1 = __expf(s[13] - 16.f);
        p2 = __expf(s[14] - 16.f); p3 = __expf(s[15] - 16.f);
        lac += (p0 + p1) + (p2 + p3);
        pk3l = pack2(p0, p1); pk3h = pack2(p2, p3);
      }
      {
        uint32_t a0 = pk0l, b0 = pk1l, a1 = pk0h, b1 = pk1h;
        asm volatile("v_permlane32_swap_b32 %0, %1" : "+v"(a0), "+v"(b0));
        asm volatile("v_permlane32_swap_b32 %0, %1" : "+v"(a1), "+v"(b1));
        union { bf16x8 v; uint32_t u[4]; } pa;
        pa.u[0] = a0; pa.u[1] = a1; pa.u[2] = b0; pa.u[3] = b1;
        __builtin_amdgcn_s_setprio(1);
#pragma unroll
        for (int dt = 0; dt < 8; ++dt) {
          bf16x8 vb = *(const bf16x8*)(&VL[buf][(h * 256 + dt * 32 + r32) * 8]);
          o[dt] = __builtin_amdgcn_mfma_f32_32x32x16_bf16(pa.v, vb, o[dt], 0, 0, 0);
        }
        __builtin_amdgcn_s_setprio(0);
      }
      {
        uint32_t a0 = pk2l, b0 = pk3l, a1 = pk2h, b1 = pk3h;
        asm volatile("v_permlane32_swap_b32 %0, %1" : "+v"(a0), "+v"(b0));
        asm volatile("v_permlane32_swap_b32 %0, %1" : "+v"(a1), "+v"(b1));
        union { bf16x8 v; uint32_t u[4]; } pa;
        pa.u[0] = a0; pa.u[1] = a1; pa.u[2] = b0; pa.u[3] = b1;
        __builtin_amdgcn_s_setprio(1);
#pragma unroll
        for (int dt = 0; dt < 8; ++dt) {
          bf16x8 vb = *(const bf16x8*)(&VL[buf][((2 + h) * 256 + dt * 32 + r32) * 8]);
          o[dt] = __builtin_amdgcn_mfma_f32_32x32x16_bf16(pa.v, vb, o[dt], 0, 0, 0);
        }
        __builtin_amdgcn_s_setprio(0);
      }
    }

    __builtin_amdgcn_sched_barrier(0);
    __builtin_amdgcn_s_barrier();
    __builtin_amdgcn_sched_barrier(0);
    if (!more) break;
    buf ^= 1;
    ci = cin;
  }

  const float lacF = lac + __shfl_xor(lac, 32, 64);
  unsigned short* pow = po + ((size_t)bid * 128 + (wave << 5)) * DIM;
  float* plw = pl + (size_t)bid * 128 + (wave << 5);
  if (h == 0) plw[r32] = lacF;
#pragma unroll
  for (int r = 0; r < 16; ++r) {
    const int srow = (r & 3) + 8 * (r >> 2) + 4 * h;
#pragma unroll
    for (int dt = 0; dt < 8; ++dt)
      pow[(size_t)srow * DIM + dt * 32 + r32] = f2bf(o[dt][r]);
  }
}

// ---- combine: straight sum over a tile's splits, normalize; block 0 row 0
// (row-0 tail parallelized: unrolled partial reduce + 4-wave split dot) ----
template <int CH>
__global__ __launch_bounds__(256) void k_comb(const unsigned short* __restrict__ po,
    const float* __restrict__ pl, const float* __restrict__ partial,
    const float* __restrict__ Wv, float* __restrict__ out, int n) {
  const int row = blockIdx.x * 16 + (threadIdx.x >> 4);
  const int c0 = (threadIdx.x & 15) * 16;
  const int t = row >> 7;
  int cumt = 0;
  for (int u = 0; u < t; ++u) cumt += (4 * u + 4 + CH - 1) / CH;
  const int ns = (4 * t + 4 + CH - 1) / CH;
  const int lr = row & 127;

  float acc[16];
#pragma unroll
  for (int j = 0; j < 16; ++j) acc[j] = 0.f;
  float lsum = 0.f;
  for (int s = 0; s < ns; ++s) {
    lsum += pl[(size_t)(cumt + s) * 128 + lr];
    const unsigned short* pp = po + ((size_t)(cumt + s) * 128 + lr) * DIM + c0;
    bf16x8 v0 = *(const bf16x8*)(pp);
    bf16x8 v1 = *(const bf16x8*)(pp + 8);
#pragma unroll
    for (int j = 0; j < 8; ++j) {
      union { float f; uint32_t u; } cv0, cv1;
      cv0.u = ((uint32_t)(unsigned short)v0[j]) << 16;
      cv1.u = ((uint32_t)(unsigned short)v1[j]) << 16;
      acc[j]     += cv0.f;
      acc[8 + j] += cv1.f;
    }
  }
  const float inv = (lsum > 0.f) ? 1.0f / lsum : 0.f;
#pragma unroll
  for (int j = 0; j < 16; ++j)
    out[(size_t)row * DIM + c0 + j] = acc[j] * inv;

  if (blockIdx.x == 0) {   // exact row 0: mean(x) @ Wv, parallel across waves
    __shared__ float xm[DIM];
    __shared__ float red[4][DIM];
    const int tid = threadIdx.x;
    const int wv = tid >> 6;
    const int ln = tid & 63;
    const int nb = n / 128;
    float s = 0.f;
#pragma unroll 8
    for (int b = 0; b < nb; ++b) s += partial[b * DIM + tid];
    xm[tid] = s / (float)n;
    __syncthreads();
    f32x4 av = {0.f, 0.f, 0.f, 0.f};
#pragma unroll 8
    for (int kk = 0; kk < 64; ++kk) {
      const int k = wv * 64 + kk;
      f32x4 wvv = *(const f32x4*)(Wv + (size_t)k * DIM + ln * 4);
      const float xk = xm[k];
      av[0] += xk * wvv[0]; av[1] += xk * wvv[1];
      av[2] += xk * wvv[2]; av[3] += xk * wvv[3];
    }
    *(f32x4*)(&red[wv][ln * 4]) = av;
    __syncthreads();
    if (wv == 0) {
#pragma unroll
      for (int j = 0; j < 4; ++j)
        out[ln * 4 + j] = red[0][ln * 4 + j] + red[1][ln * 4 + j]
                        + red[2][ln * 4 + j] + red[3][ln * 4 + j];
    }
  }
}

extern "C" void kernel_launch(void* const* d_in, const int* in_sizes, int n_in,
                              void* d_out, int out_size, void* d_ws, size_t ws_size,
                              hipStream_t stream) {
  const float* x  = (const float*)d_in[0];
  const float* Wq = (const float*)d_in[1];
  const float* Wk = (const float*)d_in[2];
  const float* Wv = (const float*)d_in[3];
  float* out = (float*)d_out;
  const int n = in_sizes[0] / DIM;
  const int T = n >> 7;

  char* ws = (char*)d_ws;
  const size_t wt_bytes  = (size_t)3 * DIM * DIM * 2;
  const size_t mat_bytes = (size_t)n * DIM * 2;
  const size_t par_bytes = (size_t)(n / 128) * DIM * 4;
  const size_t base = wt_bytes + 3 * mat_bytes + par_bytes;

  unsigned short* Wt = (unsigned short*)(ws);
  unsigned short* Q  = (unsigned short*)(ws + wt_bytes);
  unsigned short* KS = (unsigned short*)(ws + wt_bytes + mat_bytes);
  unsigned short* VS = (unsigned short*)(ws + wt_bytes + 2 * mat_bytes);
  float* partial     = (float*)(ws + wt_bytes + 3 * mat_bytes);

  auto slots_for = [&](int CH) {
    int s = 0;
    for (int t = 0; t < T; ++t) s += (4 * t + 4 + CH - 1) / CH;
    return s;
  };
  const int ns18 = slots_for(18);
  const int ns36 = slots_for(36);
  const size_t need18 = base + (size_t)ns18 * 128 * 4 + (size_t)ns18 * 128 * DIM * 2;
  const size_t need36 = base + (size_t)ns36 * 128 * 4 + (size_t)ns36 * 128 * DIM * 2;
  int mode = 0, nslots = 0;
  if (ws_size >= need18)      { mode = 18; nslots = ns18; }
  else if (ws_size >= need36) { mode = 36; nslots = ns36; }
  float* pl          = (float*)(ws + base);
  unsigned short* po = (unsigned short*)(ws + base + (size_t)nslots * 128 * 4);

  hipLaunchKernelGGL(k_prep, dim3(24 + n / 128), dim3(256), 0, stream,
                     Wq, Wk, Wv, Wt, x, partial, n);
  hipLaunchKernelGGL(k_proj, dim3(n / 64, 3), dim3(256), 0, stream, x, Wt, Q, KS, VS, n);
  if (mode == 18) {
    hipLaunchKernelGGL((k_flash8<18>), dim3(nslots), dim3(256), 0, stream,
                       Q, KS, VS, po, pl, n);
    hipLaunchKernelGGL((k_comb<18>), dim3(n / 16), dim3(256), 0, stream,
                       po, pl, partial, Wv, out, n);
  } else if (mode == 36) {
    hipLaunchKernelGGL((k_flash8<36>), dim3(nslots), dim3(256), 0, stream,
                       Q, KS, VS, po, pl, n);
    hipLaunchKernelGGL((k_comb<36>), dim3(n / 16), dim3(256), 0, stream,
                       po, pl, partial, Wv, out, n);
  } else {
    hipLaunchKernelGGL(k_flash2, dim3(n / 16), dim3(512), 0, stream, Q, KS, VS, out, n);
    hipLaunchKernelGGL(k_meanB, dim3(1), dim3(256), 0, stream, partial, Wv, out, n);
  }
}

// Round 18
// 86.729 us; speedup vs baseline: 1.6939x; 1.0136x over previous
//
#include <hip/hip_runtime.h>
#include <hip/hip_bf16.h>
#include <stdint.h>

#define DIM 256

typedef float f32x4  __attribute__((ext_vector_type(4)));
typedef float f32x16 __attribute__((ext_vector_type(16)));
typedef short bf16x8 __attribute__((ext_vector_type(8)));
typedef short bf16x4 __attribute__((ext_vector_type(4)));
typedef unsigned int u32x2 __attribute__((ext_vector_type(2)));

__device__ __forceinline__ unsigned short f2bf(float f) {
  union { float f; uint32_t u; } v; v.f = f;
  uint32_t u = v.u;
  u += 0x7FFFu + ((u >> 16) & 1u);   // round-to-nearest-even
  return (unsigned short)(u >> 16);
}

// packed f32x2 -> bf16x2 (RNE), single instruction
__device__ __forceinline__ uint32_t pack2(float lo, float hi) {
  uint32_t r;
  asm("v_cvt_pk_bf16_f32 %0, %1, %2" : "=v"(r) : "v"(lo), "v"(hi));
  return r;
}

// async global->LDS, 16B per lane; LDS dest = wave-uniform base (+ lane*16 by HW)
__device__ __forceinline__ void gload16(const unsigned short* g, unsigned short* l) {
  __builtin_amdgcn_global_load_lds(
      (const __attribute__((address_space(1))) unsigned int*)g,
      (__attribute__((address_space(3))) unsigned int*)l, 16, 0, 0);
}

// ---- prep: W -> MFMA-fragment layout WF[(w*16+nt)*8+kc][512] via LDS tile
//      (blocks 0..23); x column partial sums, 128 rows/block (blocks 24..) ----
__global__ __launch_bounds__(256) void k_prep(const float* __restrict__ Wq,
    const float* __restrict__ Wk, const float* __restrict__ Wv,
    unsigned short* __restrict__ Wt, const float* __restrict__ x,
    float* __restrict__ partial, int n) {
  __shared__ unsigned short WL32[32][264];
  if (blockIdx.x < 24) {
    const int w  = blockIdx.x >> 3;
    const int kc = blockIdx.x & 7;
    const float* W = (w == 0) ? Wq : (w == 1) ? Wk : Wv;
    const int tid = threadIdx.x;
#pragma unroll
    for (int it = 0; it < 8; ++it) {
      const int row = it * 4 + (tid >> 6);
      const int col = (tid & 63) * 4;
      f32x4 v = *(const f32x4*)(W + (size_t)(kc * 32 + row) * DIM + col);
      bf16x4 b;
      b[0] = (short)f2bf(v[0]); b[1] = (short)f2bf(v[1]);
      b[2] = (short)f2bf(v[2]); b[3] = (short)f2bf(v[3]);
      *(bf16x4*)(&WL32[row][col]) = b;
    }
    __syncthreads();
    const int lane = tid & 63;
    const int ww = tid >> 6;
    const int g = lane >> 4, c = lane & 15;
#pragma unroll
    for (int jt = 0; jt < 4; ++jt) {
      const int nt = jt * 4 + ww;
      bf16x8 o;
#pragma unroll
      for (int j = 0; j < 8; ++j)
        o[j] = (short)WL32[g * 8 + j][nt * 16 + c];
      *(bf16x8*)(Wt + (size_t)((w * 16 + nt) * 8 + kc) * 512 + lane * 8) = o;
    }
  } else {
    const int b = blockIdx.x - 24, tid = threadIdx.x;
    float acc = 0.f;
    const float* xp = x + (size_t)b * 128 * DIM + tid;
#pragma unroll 8
    for (int r = 0; r < 128; ++r) acc += xp[r * DIM];
    partial[b * DIM + tid] = acc;
  }
}

// ---- projections (w = blockIdx.y): x staged once in LDS; W streamed via
// global_load_lds dbuf; ALL outputs in fragment/chunk layouts:
// QS (KS layout, scaled 1/16), KS[chunk][d/8][key][8], VS[chunk][key/8][d][8] ----
__global__ __launch_bounds__(256, 2) void k_proj(const float* __restrict__ x,
    const unsigned short* __restrict__ Wt, unsigned short* __restrict__ QS,
    unsigned short* __restrict__ KS, unsigned short* __restrict__ VS, int n) {
  __shared__ unsigned short XL[64 * 264];     // x-tile; reused as OUT stage (32KB)
  __shared__ unsigned short WL[2][16][512];   // W frags dbuf (32 KB)
  const int rb = blockIdx.x * 64;
  const int w = blockIdx.y;
  const int wave = threadIdx.x >> 6;
  const int lane = threadIdx.x & 63;
  const int g = lane >> 4;
  const int c = lane & 15;

  for (int rr = 0; rr < 16; ++rr) {
    const int r = wave * 16 + rr;
    f32x4 v = *(const f32x4*)(x + (size_t)(rb + r) * DIM + lane * 4);
    u32x2 b;
    b[0] = pack2(v[0], v[1]);
    b[1] = pack2(v[2], v[3]);
    *(u32x2*)(&XL[r * 264 + lane * 4]) = b;
  }
  __syncthreads();

  bf16x8 af[8];
#pragma unroll
  for (int kc = 0; kc < 8; ++kc)
    af[kc] = *(const bf16x8*)(&XL[(wave * 16 + c) * 264 + kc * 32 + g * 8]);

  const unsigned short* Wsrc = Wt + (size_t)w * DIM * DIM + lane * 8;
  auto stagew = [&](int buf, int p) {
#pragma unroll
    for (int q2 = 0; q2 < 4; ++q2) {
      const int m = wave * 4 + q2;
      gload16(Wsrc + (size_t)(p * 16 + m) * 512, &WL[buf][m][0]);
    }
  };

  f32x4 acc[16];
#pragma unroll
  for (int t = 0; t < 16; ++t) acc[t] = (f32x4){0.f, 0.f, 0.f, 0.f};

  stagew(0, 0);
  int buf = 0;
#pragma unroll 1
  for (int p = 0; p < 8; ++p) {
    if (p < 7) {
      stagew(buf ^ 1, p + 1);
      asm volatile("s_waitcnt vmcnt(4)" ::: "memory");
    } else {
      asm volatile("s_waitcnt vmcnt(0)" ::: "memory");
    }
    __builtin_amdgcn_sched_barrier(0);
    __builtin_amdgcn_s_barrier();
    __builtin_amdgcn_sched_barrier(0);
#pragma unroll
    for (int q = 0; q < 2; ++q) {
      const int nt = p * 2 + q;
#pragma unroll
      for (int kc = 0; kc < 8; ++kc) {
        bf16x8 b = *(const bf16x8*)(&WL[buf][q * 8 + kc][lane * 8]);
        acc[nt] = __builtin_amdgcn_mfma_f32_16x16x32_bf16(af[kc], b, acc[nt], 0, 0, 0);
      }
    }
    __builtin_amdgcn_sched_barrier(0);
    __builtin_amdgcn_s_barrier();
    __builtin_amdgcn_sched_barrier(0);
    buf ^= 1;
  }

  // ---- epilogue: scatter acc into XL in the DEST layout, then stream out ----
  if (w == 2) {
    const int j0 = wave * 16 + 4 * g;
    const int vbase = (j0 >> 5) * 8192 + ((j0 >> 3) & 3) * 2048 + (j0 & 7);
#pragma unroll
    for (int nt = 0; nt < 16; ++nt) {
      const int col = nt * 16 + c;
      u32x2 pv;
      pv[0] = pack2(acc[nt][0], acc[nt][1]);
      pv[1] = pack2(acc[nt][2], acc[nt][3]);
      *(u32x2*)(&XL[vbase + col * 8]) = pv;
    }
  } else {
    // QS and KS share the chunk-granule fragment layout (QS scaled by 1/16)
    const float sc = (w == 0) ? 0.0625f : 1.0f;
    const int lrB = wave * 16 + 4 * g;
#pragma unroll
    for (int nt = 0; nt < 16; ++nt) {
      const int gran = 2 * nt + (c >> 3);
#pragma unroll
      for (int r = 0; r < 4; ++r) {
        const int lr = lrB + r;
        XL[(lr >> 5) * 8192 + gran * 256 + (lr & 31) * 8 + (c & 7)] = f2bf(acc[nt][r] * sc);
      }
    }
  }
  __syncthreads();
  unsigned short* dstB = (w == 0) ? QS + (size_t)(rb >> 5) * 8192
                       : (w == 1) ? KS + (size_t)(rb >> 5) * 8192
                                  : VS + (size_t)(rb >> 5) * 8192;
#pragma unroll
  for (int it = 0; it < 8; ++it)
    *(bf16x8*)(dstB + it * 2048 + threadIdx.x * 8) =
        *(const bf16x8*)(&XL[it * 2048 + threadIdx.x * 8]);
}

// ---- row 0 exact path for fallback: out[0] = mean_n(x) @ Wv ----
__global__ void k_meanB(const float* __restrict__ partial, const float* __restrict__ Wv,
                        float* __restrict__ out, int n) {
  __shared__ float xm[DIM];
  const int tid = threadIdx.x;
  float acc = 0.f;
  const int nb = n / 128;
  for (int b = 0; b < nb; ++b) acc += partial[b * DIM + tid];
  xm[tid] = acc / (float)n;
  __syncthreads();
  float o = 0.f;
  for (int k = 0; k < DIM; ++k) o += xm[k] * Wv[k * DIM + tid];
  out[tid] = o;
}

// ---- fallback flash (QS/KS/VS layouts) ----
__global__ __launch_bounds__(512, 4) void k_flash2(const unsigned short* __restrict__ QS,
    const unsigned short* __restrict__ KS, const unsigned short* __restrict__ VS,
    float* __restrict__ out, int n) {
  __shared__ float so[4][16][257];
  __shared__ float sml[4][2][16];
  __shared__ unsigned short plds[8][16][40];

  const int wave = threadIdx.x >> 6;
  const int lane = threadIdx.x & 63;
  const int g = lane >> 4;
  const int c = lane & 15;
  const int ntiles = n >> 4;
  const int tile = ntiles - 1 - (int)blockIdx.x;
  const int qb = tile << 4;

  bf16x8 qf[8];
  const unsigned short* qp = QS + (size_t)((qb + c) >> 5) * 8192 + ((qb + c) & 31) * 8;
#pragma unroll
  for (int kc = 0; kc < 8; ++kc)
    qf[kc] = *(const bf16x8*)(qp + (4 * kc + g) * 256);

  f32x4 o[16];
#pragma unroll
  for (int t = 0; t < 16; ++t) o[t] = (f32x4){0.f, 0.f, 0.f, 0.f};
  float m_r[4] = {-1e30f, -1e30f, -1e30f, -1e30f};
  float l_r[4] = {0.f, 0.f, 0.f, 0.f};

  const int nchunk = ((qb + 14) >> 5) + 1;
  for (int kt = wave; kt < nchunk; kt += 8) {
    const int k0 = kt << 5;
    const unsigned short* kch = KS + (size_t)(k0 >> 5) * 8192;
    f32x4 s0 = {0.f, 0.f, 0.f, 0.f}, s1 = {0.f, 0.f, 0.f, 0.f};
#pragma unroll
    for (int kc = 0; kc < 8; ++kc) {
      bf16x8 kb0 = *(const bf16x8*)(kch + (4 * kc + g) * 256 + c * 8);
      bf16x8 kb1 = *(const bf16x8*)(kch + (4 * kc + g) * 256 + (16 + c) * 8);
      s0 = __builtin_amdgcn_mfma_f32_16x16x32_bf16(qf[kc], kb0, s0, 0, 0, 0);
      s1 = __builtin_amdgcn_mfma_f32_16x16x32_bf16(qf[kc], kb1, s1, 0, 0, 0);
    }
    if (k0 + 31 >= qb) {
#pragma unroll
      for (int r = 0; r < 4; ++r) {
        const int qrow = qb + 4 * g + r;
        if (k0 + c >= qrow)      s0[r] = -1e9f;
        if (k0 + 16 + c >= qrow) s1[r] = -1e9f;
      }
    }
    f32x4 p0, p1;
    float alpha[4];
#pragma unroll
    for (int r = 0; r < 4; ++r) {
      float mx = fmaxf(s0[r], s1[r]);
      mx = fmaxf(mx, __shfl_xor(mx, 1, 64));
      mx = fmaxf(mx, __shfl_xor(mx, 2, 64));
      mx = fmaxf(mx, __shfl_xor(mx, 4, 64));
      mx = fmaxf(mx, __shfl_xor(mx, 8, 64));
      const float mn = fmaxf(m_r[r], mx);
      const float a = __expf(m_r[r] - mn);
      p0[r] = __expf(s0[r] - mn);
      p1[r] = __expf(s1[r] - mn);
      float ls = p0[r] + p1[r];
      ls += __shfl_xor(ls, 1, 64);
      ls += __shfl_xor(ls, 2, 64);
      ls += __shfl_xor(ls, 4, 64);
      ls += __shfl_xor(ls, 8, 64);
      l_r[r] = l_r[r] * a + ls;
      m_r[r] = mn;
      alpha[r] = a;
    }
#pragma unroll
    for (int t = 0; t < 16; ++t) {
      o[t][0] *= alpha[0]; o[t][1] *= alpha[1];
      o[t][2] *= alpha[2]; o[t][3] *= alpha[3];
    }
#pragma unroll
    for (int r = 0; r < 4; ++r) {
      plds[wave][4 * g + r][c]      = f2bf(p0[r]);
      plds[wave][4 * g + r][16 + c] = f2bf(p1[r]);
    }
    asm volatile("s_waitcnt lgkmcnt(0)" ::: "memory");
    const bf16x8 pa = *(const bf16x8*)(&plds[wave][c][8 * g]);
    const unsigned short* vch = VS + (size_t)(k0 >> 5) * 8192 + g * 2048;
#pragma unroll
    for (int t = 0; t < 16; ++t) {
      bf16x8 vb = *(const bf16x8*)(vch + (size_t)(c + 16 * t) * 8);
      o[t] = __builtin_amdgcn_mfma_f32_16x16x32_bf16(pa, vb, o[t], 0, 0, 0);
    }
  }

  auto write_slot = [&](int s) {
#pragma unroll
    for (int r = 0; r < 4; ++r) {
      const int row = 4 * g + r;
#pragma unroll
      for (int t = 0; t < 16; ++t) so[s][row][t * 16 + c] = o[t][r];
      if (c == 0) { sml[s][0][row] = m_r[r]; sml[s][1][row] = l_r[r]; }
    }
  };
  auto merge_slot = [&](int s) {
    float aa[4], ab[4];
#pragma unroll
    for (int r = 0; r < 4; ++r) {
      const int row = 4 * g + r;
      const float mb = sml[s][0][row], lb = sml[s][1][row];
      const float ms = fmaxf(m_r[r], mb);
      aa[r] = __expf(m_r[r] - ms);
      ab[r] = __expf(mb - ms);
      l_r[r] = l_r[r] * aa[r] + lb * ab[r];
      m_r[r] = ms;
    }
#pragma unroll
    for (int t = 0; t < 16; ++t)
#pragma unroll
      for (int r = 0; r < 4; ++r)
        o[t][r] = o[t][r] * aa[r] + so[s][4 * g + r][t * 16 + c] * ab[r];
  };

  __syncthreads();
  if (wave >= 4) write_slot(wave - 4);
  __syncthreads();
  if (wave < 4) merge_slot(wave);
  __syncthreads();
  if (wave == 2 || wave == 3) write_slot(wave - 2);
  __syncthreads();
  if (wave < 2) merge_slot(wave);
  __syncthreads();
  if (wave == 1) write_slot(0);
  __syncthreads();
  if (wave == 0) {
    merge_slot(0);
#pragma unroll
    for (int r = 0; r < 4; ++r) {
      const int qrow = qb + 4 * g + r;
      if (qrow == 0) continue;
      const float inv = 1.0f / l_r[r];
#pragma unroll
      for (int t = 0; t < 16; ++t)
        out[(size_t)qrow * DIM + t * 16 + c] = o[t][r] * inv;
    }
  }
}

// ---- main flash: 32x32x16, swapped QK^T; permlane32_swap P-transpose;
// Q read COALESCED from fragment-layout QS; balanced slots ----
template <int CH>
__global__ __launch_bounds__(256, 2) void k_flash8(const unsigned short* __restrict__ QS,
    const unsigned short* __restrict__ KS, const unsigned short* __restrict__ VS,
    unsigned short* __restrict__ po, float* __restrict__ pl, int n) {
  __shared__ unsigned short KL[2][32 * 32 * 8];   // [granule d/8][key][8]
  __shared__ unsigned short VL[2][4 * 256 * 8];   // [granule key/8][d][8]

  const int wave = threadIdx.x >> 6;
  const int lane = threadIdx.x & 63;
  const int r32 = lane & 31;
  const int h   = lane >> 5;

  const int bid = (int)(gridDim.x - 1 - blockIdx.x);   // heaviest slots first
  int t = 0, cacc = 0;
  for (;;) {
    const int ns = (4 * t + 4 + CH - 1) / CH;
    if (cacc + ns > bid) break;
    cacc += ns; ++t;
  }
  const int sp = bid - cacc;
  const int nsplit = (4 * t + 4 + CH - 1) / CH;
  const int qb = t << 7;
  const int qw = qb + (wave << 5);
  const int nch = 4 * t + 4;
  const int qrow_me = qw + r32;

  // coalesced Q fragments from QS (KS-style layout): 1KB per load
  bf16x8 qf[16];
  const unsigned short* qp = QS + (size_t)((qb >> 5) + wave) * 8192 + r32 * 8;
#pragma unroll
  for (int kc = 0; kc < 16; ++kc)
    qf[kc] = *(const bf16x8*)(qp + (2 * kc + h) * 256);

  f32x16 o[8];
#pragma unroll
  for (int dt = 0; dt < 8; ++dt)
#pragma unroll
    for (int r = 0; r < 16; ++r) o[dt][r] = 0.f;
  float lac = 0.f;

  const unsigned short* Ksrc = KS + (size_t)lane * 8;
  const unsigned short* Vsrc = VS + (size_t)lane * 8;

  auto stage = [&](int buf, int k0) {
    const size_t cb = (size_t)(k0 >> 5) * 8192;
#pragma unroll
    for (int jj = 0; jj < 4; ++jj)
      gload16(Ksrc + cb + (8 * wave + 2 * jj) * 256,
              &KL[buf][(8 * wave + 2 * jj) * 256]);
#pragma unroll
    for (int jj = 0; jj < 4; ++jj)
      gload16(Vsrc + cb + wave * 2048 + jj * 512,
              &VL[buf][(wave * 256 + jj * 64) * 8]);
  };

  int ci = sp;
  stage(0, ci << 5);
  int buf = 0;
  for (;;) {
    const int k0 = ci << 5;
    const int cin = ci + nsplit;
    const bool more = (cin < nch);
    if (more) {
      stage(buf ^ 1, cin << 5);
      asm volatile("s_waitcnt vmcnt(8)" ::: "memory");
    } else {
      asm volatile("s_waitcnt vmcnt(0)" ::: "memory");
    }
    __builtin_amdgcn_sched_barrier(0);
    __builtin_amdgcn_s_barrier();
    __builtin_amdgcn_sched_barrier(0);

    if (k0 <= qw + 30) {
      f32x16 sa, sb;
#pragma unroll
      for (int r = 0; r < 16; ++r) { sa[r] = 0.f; sb[r] = 0.f; }
      __builtin_amdgcn_s_setprio(1);
#pragma unroll
      for (int kc = 0; kc < 8; ++kc) {
        bf16x8 kbA = *(const bf16x8*)(&KL[buf][((2 * kc + h) * 32 + r32) * 8]);
        bf16x8 kbB = *(const bf16x8*)(&KL[buf][((2 * kc + 16 + h) * 32 + r32) * 8]);
        sa = __builtin_amdgcn_mfma_f32_32x32x16_bf16(kbA, qf[kc], sa, 0, 0, 0);
        sb = __builtin_amdgcn_mfma_f32_32x32x16_bf16(kbB, qf[kc + 8], sb, 0, 0, 0);
      }
      __builtin_amdgcn_s_setprio(0);
      f32x16 s = sa + sb;
      if (k0 + 31 >= qw) {
#pragma unroll
        for (int r = 0; r < 16; ++r) {
          const int key = k0 + (r & 3) + 8 * (r >> 2) + 4 * h;
          if (key >= qrow_me) s[r] = -1e9f;
        }
      }
      uint32_t pk0l, pk0h, pk1l, pk1h, pk2l, pk2h, pk3l, pk3h;
      {
        float p0, p1, p2, p3;
        p0 = __expf(s[0] - 16.f);  p1 = __expf(s[1] - 16.f);
        p2 = __expf(s[2] - 16.f);  p3 = __expf(s[3] - 16.f);
        lac += (p0 + p1) + (p2 + p3);
        pk0l = pack2(p0, p1); pk0h = pack2(p2, p3);
        p0 = __expf(s[4] - 16.f);  p1 = __expf(s[5] - 16.f);
        p2 = __expf(s[6] - 16.f);  p3 = __expf(s[7] - 16.f);
        lac += (p0 + p1) + (p2 + p3);
        pk1l = pack2(p0, p1); pk1h = pack2(p2, p3);
        p0 = __expf(s[8] - 16.f);  p1 = __expf(s[9] - 16.f);
        p2 = __expf(s[10] - 16.f); p3 = __expf(s[11] - 16.f);
        lac += (p0 + p1) + (p2 + p3);
        pk2l = pack2(p0, p1); pk2h = pack2(p2, p3);
        p0 = __expf(s[12] - 16.f); p1 = __expf(s[13] - 16.f);
        p2 = __expf(s[14] - 16.f); p3 = __expf(s[15] - 16.f);
        lac += (p0 + p1) + (p2 + p3);
        pk3l = pack2(p0, p1); pk3h = pack2(p2, p3);
      }
      {
        uint32_t a0 = pk0l, b0 = pk1l, a1 = pk0h, b1 = pk1h;
        asm volatile("v_permlane32_swap_b32 %0, %1" : "+v"(a0), "+v"(b0));
        asm volatile("v_permlane32_swap_b32 %0, %1" : "+v"(a1), "+v"(b1));
        union { bf16x8 v; uint32_t u[4]; } pa;
        pa.u[0] = a0; pa.u[1] = a1; pa.u[2] = b0; pa.u[3] = b1;
        __builtin_amdgcn_s_setprio(1);
#pragma unroll
        for (int dt = 0; dt < 8; ++dt) {
          bf16x8 vb = *(const bf16x8*)(&VL[buf][(h * 256 + dt * 32 + r32) * 8]);
          o[dt] = __builtin_amdgcn_mfma_f32_32x32x16_bf16(pa.v, vb, o[dt], 0, 0, 0);
        }
        __builtin_amdgcn_s_setprio(0);
      }
      {
        uint32_t a0 = pk2l, b0 = pk3l, a1 = pk2h, b1 = pk3h;
        asm volatile("v_permlane32_swap_b32 %0, %1" : "+v"(a0), "+v"(b0));
        asm volatile("v_permlane32_swap_b32 %0, %1" : "+v"(a1), "+v"(b1));
        union { bf16x8 v; uint32_t u[4]; } pa;
        pa.u[0] = a0; pa.u[1] = a1; pa.u[2] = b0; pa.u[3] = b1;
        __builtin_amdgcn_s_setprio(1);
#pragma unroll
        for (int dt = 0; dt < 8; ++dt) {
          bf16x8 vb = *(const bf16x8*)(&VL[buf][((2 + h) * 256 + dt * 32 + r32) * 8]);
          o[dt] = __builtin_amdgcn_mfma_f32_32x32x16_bf16(pa.v, vb, o[dt], 0, 0, 0);
        }
        __builtin_amdgcn_s_setprio(0);
      }
    }

    __builtin_amdgcn_sched_barrier(0);
    __builtin_amdgcn_s_barrier();
    __builtin_amdgcn_sched_barrier(0);
    if (!more) break;
    buf ^= 1;
    ci = cin;
  }

  const float lacF = lac + __shfl_xor(lac, 32, 64);
  unsigned short* pow = po + ((size_t)bid * 128 + (wave << 5)) * DIM;
  float* plw = pl + (size_t)bid * 128 + (wave << 5);
  if (h == 0) plw[r32] = lacF;
#pragma unroll
  for (int r = 0; r < 16; ++r) {
    const int srow = (r & 3) + 8 * (r >> 2) + 4 * h;
#pragma unroll
    for (int dt = 0; dt < 8; ++dt)
      pow[(size_t)srow * DIM + dt * 32 + r32] = f2bf(o[dt][r]);
  }
}

// ---- combine: straight sum over a tile's splits, normalize; block 0 row 0
// (row-0 tail parallelized: unrolled partial reduce + 4-wave split dot) ----
template <int CH>
__global__ __launch_bounds__(256) void k_comb(const unsigned short* __restrict__ po,
    const float* __restrict__ pl, const float* __restrict__ partial,
    const float* __restrict__ Wv, float* __restrict__ out, int n) {
  const int row = blockIdx.x * 16 + (threadIdx.x >> 4);
  const int c0 = (threadIdx.x & 15) * 16;
  const int t = row >> 7;
  int cumt = 0;
  for (int u = 0; u < t; ++u) cumt += (4 * u + 4 + CH - 1) / CH;
  const int ns = (4 * t + 4 + CH - 1) / CH;
  const int lr = row & 127;

  float acc[16];
#pragma unroll
  for (int j = 0; j < 16; ++j) acc[j] = 0.f;
  float lsum = 0.f;
  for (int s = 0; s < ns; ++s) {
    lsum += pl[(size_t)(cumt + s) * 128 + lr];
    const unsigned short* pp = po + ((size_t)(cumt + s) * 128 + lr) * DIM + c0;
    bf16x8 v0 = *(const bf16x8*)(pp);
    bf16x8 v1 = *(const bf16x8*)(pp + 8);
#pragma unroll
    for (int j = 0; j < 8; ++j) {
      union { float f; uint32_t u; } cv0, cv1;
      cv0.u = ((uint32_t)(unsigned short)v0[j]) << 16;
      cv1.u = ((uint32_t)(unsigned short)v1[j]) << 16;
      acc[j]     += cv0.f;
      acc[8 + j] += cv1.f;
    }
  }
  const float inv = (lsum > 0.f) ? 1.0f / lsum : 0.f;
#pragma unroll
  for (int j = 0; j < 16; ++j)
    out[(size_t)row * DIM + c0 + j] = acc[j] * inv;

  if (blockIdx.x == 0) {   // exact row 0: mean(x) @ Wv, parallel across waves
    __shared__ float xm[DIM];
    __shared__ float red[4][DIM];
    const int tid = threadIdx.x;
    const int wv = tid >> 6;
    const int ln = tid & 63;
    const int nb = n / 128;
    float s = 0.f;
#pragma unroll 8
    for (int b = 0; b < nb; ++b) s += partial[b * DIM + tid];
    xm[tid] = s / (float)n;
    __syncthreads();
    f32x4 av = {0.f, 0.f, 0.f, 0.f};
#pragma unroll 8
    for (int kk = 0; kk < 64; ++kk) {
      const int k = wv * 64 + kk;
      f32x4 wvv = *(const f32x4*)(Wv + (size_t)k * DIM + ln * 4);
      const float xk = xm[k];
      av[0] += xk * wvv[0]; av[1] += xk * wvv[1];
      av[2] += xk * wvv[2]; av[3] += xk * wvv[3];
    }
    *(f32x4*)(&red[wv][ln * 4]) = av;
    __syncthreads();
    if (wv == 0) {
#pragma unroll
      for (int j = 0; j < 4; ++j)
        out[ln * 4 + j] = red[0][ln * 4 + j] + red[1][ln * 4 + j]
                        + red[2][ln * 4 + j] + red[3][ln * 4 + j];
    }
  }
}

extern "C" void kernel_launch(void* const* d_in, const int* in_sizes, int n_in,
                              void* d_out, int out_size, void* d_ws, size_t ws_size,
                              hipStream_t stream) {
  const float* x  = (const float*)d_in[0];
  const float* Wq = (const float*)d_in[1];
  const float* Wk = (const float*)d_in[2];
  const float* Wv = (const float*)d_in[3];
  float* out = (float*)d_out;
  const int n = in_sizes[0] / DIM;
  const int T = n >> 7;

  char* ws = (char*)d_ws;
  const size_t wt_bytes  = (size_t)3 * DIM * DIM * 2;
  const size_t mat_bytes = (size_t)n * DIM * 2;
  const size_t par_bytes = (size_t)(n / 128) * DIM * 4;
  const size_t base = wt_bytes + 3 * mat_bytes + par_bytes;

  unsigned short* Wt = (unsigned short*)(ws);
  unsigned short* QS = (unsigned short*)(ws + wt_bytes);
  unsigned short* KS = (unsigned short*)(ws + wt_bytes + mat_bytes);
  unsigned short* VS = (unsigned short*)(ws + wt_bytes + 2 * mat_bytes);
  float* partial     = (float*)(ws + wt_bytes + 3 * mat_bytes);

  auto slots_for = [&](int CH) {
    int s = 0;
    for (int t = 0; t < T; ++t) s += (4 * t + 4 + CH - 1) / CH;
    return s;
  };
  const int ns18 = slots_for(18);
  const int ns36 = slots_for(36);
  const size_t need18 = base + (size_t)ns18 * 128 * 4 + (size_t)ns18 * 128 * DIM * 2;
  const size_t need36 = base + (size_t)ns36 * 128 * 4 + (size_t)ns36 * 128 * DIM * 2;
  int mode = 0, nslots = 0;
  if (ws_size >= need18)      { mode = 18; nslots = ns18; }
  else if (ws_size >= need36) { mode = 36; nslots = ns36; }
  float* pl          = (float*)(ws + base);
  unsigned short* po = (unsigned short*)(ws + base + (size_t)nslots * 128 * 4);

  hipLaunchKernelGGL(k_prep, dim3(24 + n / 128), dim3(256), 0, stream,
                     Wq, Wk, Wv, Wt, x, partial, n);
  hipLaunchKernelGGL(k_proj, dim3(n / 64, 3), dim3(256), 0, stream, x, Wt, QS, KS, VS, n);
  if (mode == 18) {
    hipLaunchKernelGGL((k_flash8<18>), dim3(nslots), dim3(256), 0, stream,
                       QS, KS, VS, po, pl, n);
    hipLaunchKernelGGL((k_comb<18>), dim3(n / 16), dim3(256), 0, stream,
                       po, pl, partial, Wv, out, n);
  } else if (mode == 36) {
    hipLaunchKernelGGL((k_flash8<36>), dim3(nslots), dim3(256), 0, stream,
                       QS, KS, VS, po, pl, n);
    hipLaunchKernelGGL((k_comb<36>), dim3(n / 16), dim3(256), 0, stream,
                       po, pl, partial, Wv, out, n);
  } else {
    hipLaunchKernelGGL(k_flash2, dim3(n / 16), dim3(512), 0, stream, QS, KS, VS, out, n);
    hipLaunchKernelGGL(k_meanB, dim3(1), dim3(256), 0, stream, partial, Wv, out, n);
  }
}